// Round 8
// baseline (217.370 us; speedup 1.0000x reference)
//
#include <hip/hip_runtime.h>

// MoE RT-DETR FFN on MI355X (gfx950).
// E=6, D=256, H=256, TOP_K=2, ROUTER_H=128, tokens N=8*4096=32768.
//
// Round 8: expert rebuilt around async global_load_lds double-buffered B
// (block-shared staging: 16 KB/kt ONCE per block, HW DMA hides L2 latency),
// M=64 tokens/block, pair-routed (zero atomics), acts-as-A frag LDS image,
// DPP-transpose layer boundaries, predicated single-store epilogue.
// Router (split-fp16 MFMA) and convert kept from round 7 (passing, fast).

#define N_TOK 32768
#define E_EXP 6

typedef _Float16 f16x8 __attribute__((ext_vector_type(8)));
typedef float    f32x4 __attribute__((ext_vector_type(4)));
typedef unsigned int u32x4 __attribute__((ext_vector_type(4)));

// ws layout (bytes):
//   [0,256)           counts[15]
//   [WS_LIST,+1.97M)  list [15][32768] int
//   [WS_WA,+1.97M)    wA   [15][32768] float (weight of lower expert; wb=1-wa)
//   [WS_WT,+2.25M)    wt fp16 expert B-frag images [(e*3+l)][kt8][nt16][64][8]
//   [WS_R1H,+128K)    rw1 hi fp16 B-frag image [kt8][nt8][64][8]
//   [WS_R1L,+128K)    rw1 lo (x2048) fp16 image, same layout
#define WS_LIST 256
#define WS_WA   (WS_LIST + 15 * N_TOK * 4)
#define WS_WT   (WS_WA + 15 * N_TOK * 4)
#define WS_R1H  (WS_WT + 2359296)
#define WS_R1L  (WS_R1H + 131072)

__device__ __forceinline__ unsigned pack_f16x2(float x, float y) {
  unsigned short a = __builtin_bit_cast(unsigned short, (_Float16)x);
  unsigned short b = __builtin_bit_cast(unsigned short, (_Float16)y);
  return (unsigned)a | ((unsigned)b << 16);
}

// split pair: hi = fp16(x); lo = fp16((x-hi)*2048)
__device__ __forceinline__ void split_pair(float x, float y,
                                           unsigned& hi, unsigned& lo) {
  _Float16 xh = (_Float16)x, yh = (_Float16)y;
  float xl = (x - (float)xh) * 2048.f, yl = (y - (float)yh) * 2048.f;
  hi = (unsigned)__builtin_bit_cast(unsigned short, xh) |
       ((unsigned)__builtin_bit_cast(unsigned short, yh) << 16);
  lo = pack_f16x2(xl, yl);
}

// async global->LDS, 16B/lane; LDS dst = wave-uniform base + lane*16.
__device__ __forceinline__ void async_cp16(const void* g, void* l) {
  __builtin_amdgcn_global_load_lds(
      (__attribute__((address_space(1))) void*)(void*)(g),
      (__attribute__((address_space(3))) void*)(l),
      16, 0, 0);
}

// ---------------------------------------------------------------------------
// K1: blocks 0..143: expert weights fp32 [E][256][256] -> fp16 B-frag images
//     img[kt][nt][L][j] = W[kt*32+(L>>4)*8+j][nt*16+(L&15)].
// blocks 144..151: router w1 [256][128] -> hi/lo split B-frag images.
// block 0 also zeroes counts[15].
// ---------------------------------------------------------------------------
__global__ __launch_bounds__(256) void convert_w_kernel(
    const float* __restrict__ w1, const float* __restrict__ w2,
    const float* __restrict__ w3, const float* __restrict__ rw1,
    _Float16* __restrict__ wt, _Float16* __restrict__ r1h,
    _Float16* __restrict__ r1l, int* __restrict__ counts) {
  __shared__ __align__(16) float xs[32 * 256];
  int blk = blockIdx.x;
  int t = threadIdx.x;
  if (blk == 0 && t < 16) counts[t] = 0;
  float4* xs4 = (float4*)xs;
  if (blk < 144) {
    int kt = blk & 7, el = blk >> 3, l = el % 3, e = el / 3;
    const float* W = (l == 0 ? w1 : (l == 1 ? w2 : w3)) +
                     (size_t)e * 65536 + (size_t)kt * 32 * 256;
    const float4* s4 = (const float4*)W;
    #pragma unroll
    for (int j = 0; j < 8; ++j) xs4[j * 256 + t] = s4[j * 256 + t];
    __syncthreads();
    _Float16* dst = wt + ((size_t)(e * 3 + l) * 8 + kt) * 8192;
    #pragma unroll
    for (int si = 0; si < 4; ++si) {
      int S = si * 256 + t;             // slot = nt*64 + L
      int Ls = S & 63;
      int n = ((S >> 6) << 4) + (Ls & 15);
      int qq = Ls >> 4;
      u32x4 pk;
      #pragma unroll
      for (int i = 0; i < 4; ++i) {
        float x = xs[(qq * 8 + 2 * i) * 256 + n];
        float y = xs[(qq * 8 + 2 * i + 1) * 256 + n];
        pk[i] = pack_f16x2(x, y);
      }
      *(u32x4*)(dst + S * 8) = pk;
    }
  } else {
    int kt = blk - 144;                 // 0..7
    const float4* s4 = (const float4*)(rw1 + (size_t)kt * 32 * 128);
    #pragma unroll
    for (int j = 0; j < 4; ++j) xs4[j * 256 + t] = s4[j * 256 + t];
    __syncthreads();
    #pragma unroll
    for (int si = 0; si < 2; ++si) {
      int S = si * 256 + t;             // slot = nt*64 + L (512 slots)
      int Ls = S & 63;
      int n = ((S >> 6) << 4) + (Ls & 15);
      int qq = Ls >> 4;
      u32x4 ph, pl;
      #pragma unroll
      for (int i = 0; i < 4; ++i) {
        float x = xs[(qq * 8 + 2 * i) * 128 + n];
        float y = xs[(qq * 8 + 2 * i + 1) * 128 + n];
        unsigned hi, lo;
        split_pair(x, y, hi, lo);
        ph[i] = hi; pl[i] = lo;
      }
      size_t off = (size_t)kt * 4096 + S * 8;
      *(u32x4*)(r1h + off) = ph;
      *(u32x4*)(r1l + off) = pl;
    }
  }
}

// ---------------------------------------------------------------------------
// K2: router. 512 blocks x 256 thr, 64 tokens/block. Layer-1 via split-fp16
// MFMA (3 products, fp32 acc). A-images: Ahi/Alo 32 KB each in a 64 KB smem
// union; rh (64x132 fp32) reuses the union after the k-loop.
// ---------------------------------------------------------------------------
__global__ __launch_bounds__(256) void router_kernel(
    const float* __restrict__ feat, const _Float16* __restrict__ r1h,
    const _Float16* __restrict__ r1l, const float* __restrict__ rb1,
    const float* __restrict__ rw2, const float* __restrict__ rb2,
    int* __restrict__ counts, int* __restrict__ list,
    float* __restrict__ wA) {
  __shared__ __align__(16) char smem[65536];         // Ahi|Alo, then rh
  __shared__ float plg[64 * 25];                     // partial logits
  __shared__ int lcnt[15], gbase[15];
  _Float16* Ahi = (_Float16*)smem;                   // 32 KB [kt8][rt4][64][8]
  _Float16* Alo = (_Float16*)(smem + 32768);         // 32 KB
  float* rh = (float*)smem;                          // reused after k-loop

  int tid = threadIdx.x;
  int wv = tid >> 6, L = tid & 63, m = L & 15, q = L >> 4;
  int tok0 = blockIdx.x * 64;

  // stage x: split fp32 -> (hi, lo*2048) fp16 A-frag images
  {
    int row = tid >> 2, seg = tid & 3;
    int rt = row >> 4, mm = row & 15;
    const float4* src = (const float4*)(feat + (size_t)(tok0 + row) * 256 + seg * 64);
    #pragma unroll
    for (int i = 0; i < 8; ++i) {
      float4 a = src[2 * i], b = src[2 * i + 1];
      u32x4 ph, pl;
      unsigned h0, l0;
      split_pair(a.x, a.y, h0, l0); ph[0] = h0; pl[0] = l0;
      split_pair(a.z, a.w, h0, l0); ph[1] = h0; pl[1] = l0;
      split_pair(b.x, b.y, h0, l0); ph[2] = h0; pl[2] = l0;
      split_pair(b.z, b.w, h0, l0); ph[3] = h0; pl[3] = l0;
      int k = seg * 64 + i * 8;
      int off = (((k >> 5) * 4 + rt) * 64 + ((k >> 3) & 3) * 16 + mm) * 8;
      *(u32x4*)(Ahi + off) = ph;
      *(u32x4*)(Alo + off) = pl;
    }
  }
  if (tid < 15) lcnt[tid] = 0;

  auto ldH = [&](int kt, int ct) -> f16x8 {
    return *(const f16x8*)(r1h + ((kt * 8 + wv * 2 + ct) * 64 + L) * 8);
  };
  auto ldL = [&](int kt, int ct) -> f16x8 {
    return *(const f16x8*)(r1l + ((kt * 8 + wv * 2 + ct) * 64 + L) * 8);
  };
  f16x8 bch[2], bcl[2];
  #pragma unroll
  for (int ct = 0; ct < 2; ++ct) { bch[ct] = ldH(0, ct); bcl[ct] = ldL(0, ct); }
  __syncthreads();                      // A images staged

  f32x4 ach[4][2], acm[4][2];
  #pragma unroll
  for (int ct = 0; ct < 2; ++ct) {
    float bv = rb1[wv * 32 + ct * 16 + m];
    #pragma unroll
    for (int rt = 0; rt < 4; ++rt) {
      ach[rt][ct][0] = bv; ach[rt][ct][1] = bv;
      ach[rt][ct][2] = bv; ach[rt][ct][3] = bv;
      acm[rt][ct][0] = 0.f; acm[rt][ct][1] = 0.f;
      acm[rt][ct][2] = 0.f; acm[rt][ct][3] = 0.f;
    }
  }
  #pragma unroll
  for (int kt = 0; kt < 8; ++kt) {
    f16x8 bnh[2], bnl[2];
    if (kt < 7) {
      #pragma unroll
      for (int ct = 0; ct < 2; ++ct) { bnh[ct] = ldH(kt + 1, ct); bnl[ct] = ldL(kt + 1, ct); }
    }
    f16x8 ah[4], al[4];
    #pragma unroll
    for (int rt = 0; rt < 4; ++rt) {
      ah[rt] = *(const f16x8*)(Ahi + ((kt * 4 + rt) * 64 + L) * 8);
      al[rt] = *(const f16x8*)(Alo + ((kt * 4 + rt) * 64 + L) * 8);
    }
    #pragma unroll
    for (int rt = 0; rt < 4; ++rt)
      #pragma unroll
      for (int ct = 0; ct < 2; ++ct)
        ach[rt][ct] = __builtin_amdgcn_mfma_f32_16x16x32_f16(
            ah[rt], bch[ct], ach[rt][ct], 0, 0, 0);
    #pragma unroll
    for (int rt = 0; rt < 4; ++rt)
      #pragma unroll
      for (int ct = 0; ct < 2; ++ct) {
        acm[rt][ct] = __builtin_amdgcn_mfma_f32_16x16x32_f16(
            ah[rt], bcl[ct], acm[rt][ct], 0, 0, 0);
        acm[rt][ct] = __builtin_amdgcn_mfma_f32_16x16x32_f16(
            al[rt], bch[ct], acm[rt][ct], 0, 0, 0);
      }
    if (kt < 7) {
      #pragma unroll
      for (int ct = 0; ct < 2; ++ct) { bch[ct] = bnh[ct]; bcl[ct] = bnl[ct]; }
    }
  }
  __syncthreads();                      // all A reads done; reuse smem as rh

  #pragma unroll
  for (int rt = 0; rt < 4; ++rt)
    #pragma unroll
    for (int ct = 0; ct < 2; ++ct)
      #pragma unroll
      for (int r = 0; r < 4; ++r) {
        float v = ach[rt][ct][r] + acm[rt][ct][r] * (1.f / 2048.f);
        int row = rt * 16 + q * 4 + r, h = wv * 32 + ct * 16 + m;
        rh[row * 132 + h] = fmaxf(v, 0.f);
      }
  __syncthreads();

  // layer 2: 4 threads per token, 32 h each
  {
    int t = tid >> 2, sub = tid & 3;
    float lgp[E_EXP] = {0.f, 0.f, 0.f, 0.f, 0.f, 0.f};
    #pragma unroll
    for (int c = 0; c < 8; ++c) {
      int c4 = sub * 8 + c;
      float4 xv = *(const float4*)(rh + t * 132 + c4 * 4);
      #pragma unroll
      for (int j = 0; j < 4; ++j) {
        float xj = (j == 0) ? xv.x : (j == 1) ? xv.y : (j == 2) ? xv.z : xv.w;
        const float* wr = rw2 + (c4 * 4 + j) * E_EXP;
        #pragma unroll
        for (int e2 = 0; e2 < E_EXP; ++e2)
          lgp[e2] = fmaf(xj, wr[e2], lgp[e2]);
      }
    }
    float* pp = plg + t * 25 + sub * 6;
    #pragma unroll
    for (int e2 = 0; e2 < E_EXP; ++e2) pp[e2] = lgp[e2];
  }
  __syncthreads();

  int pid = 0, loc = 0, token = 0;
  float wa = 0.f;
  if (tid < 64) {
    token = tok0 + tid;
    float p[E_EXP];
    float mx = -1e30f;
    #pragma unroll
    for (int i = 0; i < E_EXP; ++i) {
      p[i] = rb2[i] + plg[tid * 25 + i] + plg[tid * 25 + 6 + i] +
             plg[tid * 25 + 12 + i] + plg[tid * 25 + 18 + i];
      mx = fmaxf(mx, p[i]);
    }
    float sum = 0.f;
    #pragma unroll
    for (int i = 0; i < E_EXP; ++i) { p[i] = expf(p[i] - mx); sum += p[i]; }
    float inv = 1.f / sum;
    #pragma unroll
    for (int i = 0; i < E_EXP; ++i) p[i] *= inv;
    float b1v = p[0]; int sel0 = 0;
    #pragma unroll
    for (int i = 1; i < E_EXP; ++i) if (p[i] > b1v) { b1v = p[i]; sel0 = i; }
    float b2v = -1.f; int sel1 = 0;
    #pragma unroll
    for (int i = 0; i < E_EXP; ++i)
      if (i != sel0 && p[i] > b2v) { b2v = p[i]; sel1 = i; }
    float r = expf(b2v - b1v);          // softmax over the two top probs
    float sw0 = 1.f / (1.f + r);
    float sw1 = r / (1.f + r);
    int a = sel0 < sel1 ? sel0 : sel1;
    int b = sel0 < sel1 ? sel1 : sel0;
    wa = (sel0 < sel1) ? sw0 : sw1;     // weight of lower-index expert
    pid = b * (b - 1) / 2 + a;
    loc = atomicAdd(&lcnt[pid], 1);
  }
  __syncthreads();
  if (tid < 15) gbase[tid] = atomicAdd(&counts[tid], lcnt[tid]);
  __syncthreads();
  if (tid < 64) {
    int p0 = gbase[pid] + loc;
    list[pid * N_TOK + p0] = token;
    wA[pid * N_TOK + p0] = wa;
  }
}

// ---------------------------------------------------------------------------
// K3: pair-fused grouped GEMM. Block = 256 thr (4 waves), 64 tokens/block,
// one expert PAIR, two passes. A (acts) in 32 KB frag LDS; B (weights) in a
// 2x16 KB LDS double buffer streamed with async global_load_lds (staged once
// per block per kt -- block-shared, DMA-latency-hidden). DPP-transpose layer
// boundaries; predicated single f32x4 stores. No atomics.
// ---------------------------------------------------------------------------
__global__ __launch_bounds__(256, 2) void expert_kernel(
    const float* __restrict__ feat, const _Float16* __restrict__ wt,
    const float* __restrict__ eb1, const float* __restrict__ eb2,
    const float* __restrict__ eb3, const int* __restrict__ counts,
    const int* __restrict__ list, const float* __restrict__ wA,
    float* __restrict__ out) {
  __shared__ __align__(16) _Float16 Ah[16384];    // [kt8][rt4][64][8], 32 KB
  __shared__ __align__(16) _Float16 Bh[2][8192];  // [nt16][64][8], 2 x 16 KB
  __shared__ int   toks[64];
  __shared__ float wgA[64];

  const int loT[15] = {0,0,1,0,1,2,0,1,2,3,0,1,2,3,4};
  const int hiT[15] = {1,2,2,3,3,3,4,4,4,4,5,5,5,5,5};

  int bid = blockIdx.x;
  int pid = 0, tile = 0, cnt = 0, cum = 0;
  #pragma unroll
  for (int i = 0; i < 15; ++i) {
    int ci = counts[i];
    int nt = (ci + 63) >> 6;
    bool hit = (bid >= cum) && (bid < cum + nt);
    if (hit) { pid = i; tile = bid - cum; cnt = ci; }
    cum += nt;
  }
  if (bid >= cum) return;
  int base = tile * 64;
  int eLo = loT[pid], eHi = hiT[pid];

  int tid = threadIdx.x;
  int wv = tid >> 6, L = tid & 63, m = L & 15, q = L >> 4;
  int wcol = wv * 64;

  if (tid < 64) {
    int idx = base + tid;
    int tk = 0; float a = 0.f;
    if (idx < cnt) { tk = list[pid * N_TOK + idx]; a = wA[pid * N_TOK + idx]; }
    toks[tid] = tk; wgA[tid] = a;       // w==0 pad rows never stored
  }

  // flat step s = pass*24 + l*8 + kt
  auto stageB = [&](int s, int buf) {
    int ee = (s >= 24) ? eHi : eLo;
    int ss = (s >= 24) ? s - 24 : s;
    const _Float16* src = wt + ((size_t)ee * 24 + ss) * 8192;
    #pragma unroll
    for (int j = 0; j < 4; ++j) {       // 16 KB = 1024 lanes * 16 B
      int c = j * 256 + tid;
      async_cp16(src + c * 8, &Bh[buf][c * 8]);
    }
  };

  // gather 64 token rows fp32 -> fp16 natural frag image (overwrites Ah)
  auto stageA = [&]() {
    int row = tid >> 2, seg = tid & 3;
    int rt = row >> 4, mm = row & 15;
    const float* srcr = feat + (size_t)toks[row] * 256 + seg * 64;
    #pragma unroll
    for (int i = 0; i < 8; ++i) {
      int k = seg * 64 + i * 8;
      float4 a = *(const float4*)(srcr + i * 8);
      float4 b = *(const float4*)(srcr + i * 8 + 4);
      u32x4 pk;
      pk[0] = pack_f16x2(a.x, a.y);
      pk[1] = pack_f16x2(a.z, a.w);
      pk[2] = pack_f16x2(b.x, b.y);
      pk[3] = pack_f16x2(b.z, b.w);
      int off = (((k >> 5) * 4 + rt) * 64 + ((k >> 3) & 3) * 16 + mm) * 8;
      *(u32x4*)(Ah + off) = pk;
    }
  };

  __syncthreads();                      // toks/wgA visible
  stageA();
  stageB(0, 0);
  __syncthreads();                      // A image + B0 ready

  f32x4 acc[4][4], accS[4][4];          // [rt][ct]
  int s = 0;

  #pragma unroll
  for (int pass = 0; pass < 2; ++pass) {
    int e = pass ? eHi : eLo;
    const float* bias[3] = {eb1 + e * 256, eb2 + e * 256, eb3 + e * 256};

    #pragma unroll
    for (int l = 0; l < 3; ++l) {
      #pragma unroll
      for (int ct = 0; ct < 4; ++ct) {
        float bv = bias[l][wcol + ct * 16 + m];
        #pragma unroll
        for (int rt = 0; rt < 4; ++rt) {
          acc[rt][ct][0] = bv; acc[rt][ct][1] = bv;
          acc[rt][ct][2] = bv; acc[rt][ct][3] = bv;
        }
      }
      #pragma unroll
      for (int kt = 0; kt < 8; ++kt, ++s) {
        if (s + 1 < 48) stageB(s + 1, (s + 1) & 1);   // DMA next B tile
        const _Float16* Bb = Bh[s & 1];
        f16x8 bf[4];
        #pragma unroll
        for (int ct = 0; ct < 4; ++ct)
          bf[ct] = *(const f16x8*)(Bb + ((wv * 4 + ct) * 64 + L) * 8);
        f16x8 af[4];
        #pragma unroll
        for (int rt = 0; rt < 4; ++rt)
          af[rt] = *(const f16x8*)(Ah + ((kt * 4 + rt) * 64 + L) * 8);
        #pragma unroll
        for (int rt = 0; rt < 4; ++rt)
          #pragma unroll
          for (int ct = 0; ct < 4; ++ct)
            acc[rt][ct] = __builtin_amdgcn_mfma_f32_16x16x32_f16(
                af[rt], bf[ct], acc[rt][ct], 0, 0, 0);
        __syncthreads();                // next B staged & all reads done
      }
      if (l < 2) {
        // 4x4 in-register transpose (shfl_xor) -> relu+pack -> b64 stores
        int i = m & 3;
        bool s1 = (i & 2) != 0, s2 = (i & 1) != 0;
        #pragma unroll
        for (int rt = 0; rt < 4; ++rt) {
          #pragma unroll
          for (int ct = 0; ct < 4; ++ct) {
            float x0 = acc[rt][ct][0], x1 = acc[rt][ct][1];
            float x2 = acc[rt][ct][2], x3 = acc[rt][ct][3];
            float t0 = __shfl_xor(x2, 2), t1 = __shfl_xor(x3, 2);
            float t2 = __shfl_xor(x0, 2), t3 = __shfl_xor(x1, 2);
            x0 = s1 ? t0 : x0;  x1 = s1 ? t1 : x1;
            x2 = s1 ? x2 : t2;  x3 = s1 ? x3 : t3;
            float u0 = __shfl_xor(x1, 1), u1 = __shfl_xor(x0, 1);
            float u2 = __shfl_xor(x3, 1), u3 = __shfl_xor(x2, 1);
            x0 = s2 ? u0 : x0;  x1 = s2 ? x1 : u1;
            x2 = s2 ? u2 : x2;  x3 = s2 ? x3 : u3;
            uint2 pk;
            pk.x = pack_f16x2(fmaxf(x0, 0.f), fmaxf(x1, 0.f));
            pk.y = pack_f16x2(fmaxf(x2, 0.f), fmaxf(x3, 0.f));
            int n0 = wcol + ct * 16 + (m & ~3);   // next-layer k (4 consecutive)
            int m2 = q * 4 + i;                   // token row within tile rt
            int off = (((n0 >> 5) * 4 + rt) * 64 + ((n0 >> 3) & 3) * 16 + m2) * 8 +
                      (n0 & 7);
            *(uint2*)(Ah + off) = pk;
          }
        }
        __syncthreads();                // writeback visible
      }
    }

    if (pass == 0) {
      #pragma unroll
      for (int rt = 0; rt < 4; ++rt)
        #pragma unroll
        for (int r = 0; r < 4; ++r) {
          float wa = wgA[rt * 16 + q * 4 + r];
          #pragma unroll
          for (int ct = 0; ct < 4; ++ct)
            accS[rt][ct][r] = acc[rt][ct][r] * wa;
        }
      stageA();                         // re-gather acts for pass 1
      __syncthreads();
    } else {
      #pragma unroll
      for (int rt = 0; rt < 4; ++rt)
        #pragma unroll
        for (int r = 0; r < 4; ++r) {
          float wb = 1.f - wgA[rt * 16 + q * 4 + r];
          #pragma unroll
          for (int ct = 0; ct < 4; ++ct)
            acc[rt][ct][r] = accS[rt][ct][r] + acc[rt][ct][r] * wb;
        }
    }
  }

  // final DPP transpose + predicated f32x4 stores (each row exactly once)
  {
    int i = m & 3;
    bool s1 = (i & 2) != 0, s2 = (i & 1) != 0;
    #pragma unroll
    for (int rt = 0; rt < 4; ++rt) {
      int row = rt * 16 + q * 4 + i;
      bool valid = (base + row) < cnt;
      #pragma unroll
      for (int ct = 0; ct < 4; ++ct) {
        float x0 = acc[rt][ct][0], x1 = acc[rt][ct][1];
        float x2 = acc[rt][ct][2], x3 = acc[rt][ct][3];
        float t0 = __shfl_xor(x2, 2), t1 = __shfl_xor(x3, 2);
        float t2 = __shfl_xor(x0, 2), t3 = __shfl_xor(x1, 2);
        x0 = s1 ? t0 : x0;  x1 = s1 ? t1 : x1;
        x2 = s1 ? x2 : t2;  x3 = s1 ? x3 : t3;
        float u0 = __shfl_xor(x1, 1), u1 = __shfl_xor(x0, 1);
        float u2 = __shfl_xor(x3, 1), u3 = __shfl_xor(x2, 1);
        x0 = s2 ? u0 : x0;  x1 = s2 ? x1 : u1;
        x2 = s2 ? u2 : x2;  x3 = s2 ? x3 : u3;
        if (valid) {
          float4 v = make_float4(x0, x1, x2, x3);
          *(float4*)(out + (size_t)toks[row] * 256 + wcol + ct * 16 + (m & ~3)) = v;
        }
      }
    }
  }
}

extern "C" void kernel_launch(void* const* d_in, const int* in_sizes, int n_in,
                              void* d_out, int out_size, void* d_ws, size_t ws_size,
                              hipStream_t stream) {
  const float* feat = (const float*)d_in[0];
  const float* rw1  = (const float*)d_in[1];
  const float* rb1  = (const float*)d_in[2];
  const float* rw2  = (const float*)d_in[3];
  const float* rb2  = (const float*)d_in[4];
  const float* ew1  = (const float*)d_in[5];
  const float* eb1  = (const float*)d_in[6];
  const float* ew2  = (const float*)d_in[7];
  const float* eb2  = (const float*)d_in[8];
  const float* ew3  = (const float*)d_in[9];
  const float* eb3  = (const float*)d_in[10];
  float* out = (float*)d_out;

  char* ws = (char*)d_ws;
  int*      counts = (int*)(ws);
  int*      list   = (int*)(ws + WS_LIST);
  float*    wA     = (float*)(ws + WS_WA);
  _Float16* wt     = (_Float16*)(ws + WS_WT);
  _Float16* r1h    = (_Float16*)(ws + WS_R1H);
  _Float16* r1l    = (_Float16*)(ws + WS_R1L);

  convert_w_kernel<<<152, 256, 0, stream>>>(ew1, ew2, ew3, rw1, wt, r1h, r1l,
                                            counts);
  router_kernel<<<N_TOK / 64, 256, 0, stream>>>(feat, r1h, r1l, rb1, rw2, rb2,
                                                counts, list, wA);
  // 32768 tokens -> <=512 full tiles + <=15 ragged: 527 blocks covers all.
  expert_kernel<<<527, 256, 0, stream>>>(
      feat, wt, eb1, eb2, eb3, counts, list, wA, out);
}

// Round 9
// 181.737 us; speedup vs baseline: 1.1961x; 1.1961x over previous
//
#include <hip/hip_runtime.h>

// MoE RT-DETR FFN on MI355X (gfx950).
// E=6, D=256, H=256, TOP_K=2, ROUTER_H=128, tokens N=8*4096=32768.
//
// Round 9: expert = v7 register-prefetch k-loop (best, no per-kt barriers)
// with depth-3 B pipeline, dual A-image (A0 preserved acts + W working buffer
// -> no pass-1 re-gather, fewer barriers), accS packed f16. Router resized to
// 32 tokens/block (4 blocks/CU residency). Pair-routed, zero atomics in the
// expert path, output stored exactly once.

#define N_TOK 32768
#define E_EXP 6

typedef _Float16 f16x8 __attribute__((ext_vector_type(8)));
typedef _Float16 f16x4 __attribute__((ext_vector_type(4)));
typedef float    f32x4 __attribute__((ext_vector_type(4)));
typedef unsigned int u32x4 __attribute__((ext_vector_type(4)));

// ws layout (bytes):
//   [0,256)           counts[15]
//   [WS_LIST,+1.97M)  list [15][32768] int
//   [WS_WA,+1.97M)    wA   [15][32768] float (weight of lower expert; wb=1-wa)
//   [WS_WT,+2.25M)    wt fp16 expert B-frag images [(e*3+l)][kt8][nt16][64][8]
//   [WS_R1H,+128K)    rw1 hi fp16 B-frag image [kt8][nt8][64][8]
//   [WS_R1L,+128K)    rw1 lo (x2048) fp16 image, same layout
#define WS_LIST 256
#define WS_WA   (WS_LIST + 15 * N_TOK * 4)
#define WS_WT   (WS_WA + 15 * N_TOK * 4)
#define WS_R1H  (WS_WT + 2359296)
#define WS_R1L  (WS_R1H + 131072)

__device__ __forceinline__ unsigned pack_f16x2(float x, float y) {
  unsigned short a = __builtin_bit_cast(unsigned short, (_Float16)x);
  unsigned short b = __builtin_bit_cast(unsigned short, (_Float16)y);
  return (unsigned)a | ((unsigned)b << 16);
}

// split pair: hi = fp16(x); lo = fp16((x-hi)*2048)
__device__ __forceinline__ void split_pair(float x, float y,
                                           unsigned& hi, unsigned& lo) {
  _Float16 xh = (_Float16)x, yh = (_Float16)y;
  float xl = (x - (float)xh) * 2048.f, yl = (y - (float)yh) * 2048.f;
  hi = (unsigned)__builtin_bit_cast(unsigned short, xh) |
       ((unsigned)__builtin_bit_cast(unsigned short, yh) << 16);
  lo = pack_f16x2(xl, yl);
}

// ---------------------------------------------------------------------------
// K1: blocks 0..143: expert weights fp32 [E][256][256] -> fp16 B-frag images
// blocks 144..151: router w1 [256][128] -> hi/lo split B-frag images.
// block 0 also zeroes counts[15] (safe: stream-serialized before router).
// ---------------------------------------------------------------------------
__global__ __launch_bounds__(256) void convert_w_kernel(
    const float* __restrict__ w1, const float* __restrict__ w2,
    const float* __restrict__ w3, const float* __restrict__ rw1,
    _Float16* __restrict__ wt, _Float16* __restrict__ r1h,
    _Float16* __restrict__ r1l, int* __restrict__ counts) {
  __shared__ __align__(16) float xs[32 * 256];
  int blk = blockIdx.x;
  int t = threadIdx.x;
  if (blk == 0 && t < 16) counts[t] = 0;
  float4* xs4 = (float4*)xs;
  if (blk < 144) {
    int kt = blk & 7, el = blk >> 3, l = el % 3, e = el / 3;
    const float* W = (l == 0 ? w1 : (l == 1 ? w2 : w3)) +
                     (size_t)e * 65536 + (size_t)kt * 32 * 256;
    const float4* s4 = (const float4*)W;
    #pragma unroll
    for (int j = 0; j < 8; ++j) xs4[j * 256 + t] = s4[j * 256 + t];
    __syncthreads();
    _Float16* dst = wt + ((size_t)(e * 3 + l) * 8 + kt) * 8192;
    #pragma unroll
    for (int si = 0; si < 4; ++si) {
      int S = si * 256 + t;             // slot = nt*64 + L
      int Ls = S & 63;
      int n = ((S >> 6) << 4) + (Ls & 15);
      int qq = Ls >> 4;
      u32x4 pk;
      #pragma unroll
      for (int i = 0; i < 4; ++i) {
        float x = xs[(qq * 8 + 2 * i) * 256 + n];
        float y = xs[(qq * 8 + 2 * i + 1) * 256 + n];
        pk[i] = pack_f16x2(x, y);
      }
      *(u32x4*)(dst + S * 8) = pk;
    }
  } else {
    int kt = blk - 144;                 // 0..7
    const float4* s4 = (const float4*)(rw1 + (size_t)kt * 32 * 128);
    #pragma unroll
    for (int j = 0; j < 4; ++j) xs4[j * 256 + t] = s4[j * 256 + t];
    __syncthreads();
    #pragma unroll
    for (int si = 0; si < 2; ++si) {
      int S = si * 256 + t;             // slot = nt*64 + L (512 slots)
      int Ls = S & 63;
      int n = ((S >> 6) << 4) + (Ls & 15);
      int qq = Ls >> 4;
      u32x4 ph, pl;
      #pragma unroll
      for (int i = 0; i < 4; ++i) {
        float x = xs[(qq * 8 + 2 * i) * 128 + n];
        float y = xs[(qq * 8 + 2 * i + 1) * 128 + n];
        unsigned hi, lo;
        split_pair(x, y, hi, lo);
        ph[i] = hi; pl[i] = lo;
      }
      size_t off = (size_t)kt * 4096 + S * 8;
      *(u32x4*)(r1h + off) = ph;
      *(u32x4*)(r1l + off) = pl;
    }
  }
}

// ---------------------------------------------------------------------------
// K2: router. 1024 blocks x 256 thr, 32 tokens/block (LDS ~39 KB -> 4
// blocks/CU). Layer-1 via split-fp16 MFMA (fp32-grade logits at MFMA rate).
// rh reuses the A-image union. Emits pair-bucketed lists.
// ---------------------------------------------------------------------------
__global__ __launch_bounds__(256) void router_kernel(
    const float* __restrict__ feat, const _Float16* __restrict__ r1h,
    const _Float16* __restrict__ r1l, const float* __restrict__ rb1,
    const float* __restrict__ rw2, const float* __restrict__ rb2,
    int* __restrict__ counts, int* __restrict__ list,
    float* __restrict__ wA) {
  __shared__ __align__(16) char smem[32768];   // Ahi|Alo (16 KB ea), then rh
  __shared__ float plg[32 * 49];               // partial logits (8 subs/token)
  __shared__ int lcnt[15], gbase[15];
  _Float16* Ahi = (_Float16*)smem;             // [kt8][rt2][64][8]
  _Float16* Alo = (_Float16*)(smem + 16384);
  float* rh = (float*)smem;                    // [32][132], reused after k-loop

  int tid = threadIdx.x;
  int wv = tid >> 6, L = tid & 63, m = L & 15, q = L >> 4;
  int tok0 = blockIdx.x * 32;

  // stage x: split fp32 -> (hi, lo*2048) fp16 A-frag images
  {
    int row = tid >> 3, seg = tid & 7;         // 32 rows x 8 segs of 32 floats
    int rt = row >> 4, mm = row & 15;
    const float4* src = (const float4*)(feat + (size_t)(tok0 + row) * 256 + seg * 32);
    #pragma unroll
    for (int i = 0; i < 4; ++i) {
      float4 a = src[2 * i], b = src[2 * i + 1];
      u32x4 ph, pl;
      unsigned h0, l0;
      split_pair(a.x, a.y, h0, l0); ph[0] = h0; pl[0] = l0;
      split_pair(a.z, a.w, h0, l0); ph[1] = h0; pl[1] = l0;
      split_pair(b.x, b.y, h0, l0); ph[2] = h0; pl[2] = l0;
      split_pair(b.z, b.w, h0, l0); ph[3] = h0; pl[3] = l0;
      int k = seg * 32 + i * 8;
      int off = (((k >> 5) * 2 + rt) * 64 + ((k >> 3) & 3) * 16 + mm) * 8;
      *(u32x4*)(Ahi + off) = ph;
      *(u32x4*)(Alo + off) = pl;
    }
  }
  if (tid < 15) lcnt[tid] = 0;

  auto ldH = [&](int kt, int ct) -> f16x8 {
    return *(const f16x8*)(r1h + ((kt * 8 + wv * 2 + ct) * 64 + L) * 8);
  };
  auto ldL = [&](int kt, int ct) -> f16x8 {
    return *(const f16x8*)(r1l + ((kt * 8 + wv * 2 + ct) * 64 + L) * 8);
  };
  f16x8 bch[2], bcl[2];
  #pragma unroll
  for (int ct = 0; ct < 2; ++ct) { bch[ct] = ldH(0, ct); bcl[ct] = ldL(0, ct); }
  __syncthreads();                      // A images staged

  f32x4 ach[2][2], acm[2][2];
  #pragma unroll
  for (int ct = 0; ct < 2; ++ct) {
    float bv = rb1[wv * 32 + ct * 16 + m];
    #pragma unroll
    for (int rt = 0; rt < 2; ++rt) {
      ach[rt][ct][0] = bv; ach[rt][ct][1] = bv;
      ach[rt][ct][2] = bv; ach[rt][ct][3] = bv;
      acm[rt][ct][0] = 0.f; acm[rt][ct][1] = 0.f;
      acm[rt][ct][2] = 0.f; acm[rt][ct][3] = 0.f;
    }
  }
  #pragma unroll
  for (int kt = 0; kt < 8; ++kt) {
    f16x8 bnh[2], bnl[2];
    if (kt < 7) {
      #pragma unroll
      for (int ct = 0; ct < 2; ++ct) { bnh[ct] = ldH(kt + 1, ct); bnl[ct] = ldL(kt + 1, ct); }
    }
    f16x8 ah[2], al[2];
    #pragma unroll
    for (int rt = 0; rt < 2; ++rt) {
      ah[rt] = *(const f16x8*)(Ahi + ((kt * 2 + rt) * 64 + L) * 8);
      al[rt] = *(const f16x8*)(Alo + ((kt * 2 + rt) * 64 + L) * 8);
    }
    #pragma unroll
    for (int rt = 0; rt < 2; ++rt)
      #pragma unroll
      for (int ct = 0; ct < 2; ++ct) {
        ach[rt][ct] = __builtin_amdgcn_mfma_f32_16x16x32_f16(
            ah[rt], bch[ct], ach[rt][ct], 0, 0, 0);
        acm[rt][ct] = __builtin_amdgcn_mfma_f32_16x16x32_f16(
            ah[rt], bcl[ct], acm[rt][ct], 0, 0, 0);
        acm[rt][ct] = __builtin_amdgcn_mfma_f32_16x16x32_f16(
            al[rt], bch[ct], acm[rt][ct], 0, 0, 0);
      }
    if (kt < 7) {
      #pragma unroll
      for (int ct = 0; ct < 2; ++ct) { bch[ct] = bnh[ct]; bcl[ct] = bnl[ct]; }
    }
  }
  __syncthreads();                      // all A reads done; reuse smem as rh

  #pragma unroll
  for (int rt = 0; rt < 2; ++rt)
    #pragma unroll
    for (int ct = 0; ct < 2; ++ct)
      #pragma unroll
      for (int r = 0; r < 4; ++r) {
        float v = ach[rt][ct][r] + acm[rt][ct][r] * (1.f / 2048.f);
        int row = rt * 16 + q * 4 + r, h = wv * 32 + ct * 16 + m;
        rh[row * 132 + h] = fmaxf(v, 0.f);
      }
  __syncthreads();

  // layer 2: 8 threads per token, 16 h each
  {
    int t = tid >> 3, sub = tid & 7;
    float lgp[E_EXP] = {0.f, 0.f, 0.f, 0.f, 0.f, 0.f};
    #pragma unroll
    for (int c = 0; c < 4; ++c) {
      int c4 = sub * 4 + c;
      float4 xv = *(const float4*)(rh + t * 132 + c4 * 4);
      #pragma unroll
      for (int j = 0; j < 4; ++j) {
        float xj = (j == 0) ? xv.x : (j == 1) ? xv.y : (j == 2) ? xv.z : xv.w;
        const float* wr = rw2 + (c4 * 4 + j) * E_EXP;
        #pragma unroll
        for (int e2 = 0; e2 < E_EXP; ++e2)
          lgp[e2] = fmaf(xj, wr[e2], lgp[e2]);
      }
    }
    float* pp = plg + t * 49 + sub * 6;
    #pragma unroll
    for (int e2 = 0; e2 < E_EXP; ++e2) pp[e2] = lgp[e2];
  }
  __syncthreads();

  int pid = 0, loc = 0, token = 0;
  float wa = 0.f;
  if (tid < 32) {
    token = tok0 + tid;
    float p[E_EXP];
    float mx = -1e30f;
    #pragma unroll
    for (int i = 0; i < E_EXP; ++i) {
      float s = rb2[i];
      #pragma unroll
      for (int sb = 0; sb < 8; ++sb) s += plg[tid * 49 + sb * 6 + i];
      p[i] = s;
      mx = fmaxf(mx, p[i]);
    }
    float sum = 0.f;
    #pragma unroll
    for (int i = 0; i < E_EXP; ++i) { p[i] = expf(p[i] - mx); sum += p[i]; }
    float inv = 1.f / sum;
    #pragma unroll
    for (int i = 0; i < E_EXP; ++i) p[i] *= inv;
    float b1v = p[0]; int sel0 = 0;
    #pragma unroll
    for (int i = 1; i < E_EXP; ++i) if (p[i] > b1v) { b1v = p[i]; sel0 = i; }
    float b2v = -1.f; int sel1 = 0;
    #pragma unroll
    for (int i = 0; i < E_EXP; ++i)
      if (i != sel0 && p[i] > b2v) { b2v = p[i]; sel1 = i; }
    float r = expf(b2v - b1v);          // softmax over the two top probs
    float sw0 = 1.f / (1.f + r);
    float sw1 = r / (1.f + r);
    int a = sel0 < sel1 ? sel0 : sel1;
    int b = sel0 < sel1 ? sel1 : sel0;
    wa = (sel0 < sel1) ? sw0 : sw1;     // weight of lower-index expert
    pid = b * (b - 1) / 2 + a;
    loc = atomicAdd(&lcnt[pid], 1);
  }
  __syncthreads();
  if (tid < 15) gbase[tid] = atomicAdd(&counts[tid], lcnt[tid]);
  __syncthreads();
  if (tid < 32) {
    int p0 = gbase[pid] + loc;
    list[pid * N_TOK + p0] = token;
    wA[pid * N_TOK + p0] = wa;
  }
}

// ---------------------------------------------------------------------------
// K3: pair-fused grouped GEMM. Block = 256 thr (4 waves), 32 tokens/block,
// one expert PAIR, two passes. A0 = preserved acts (16 KB), W = working image
// (16 KB); layer 1 always reads A0 (no pass-1 re-gather). B (weights) stream
// global->VGPR with DEPTH-3 prefetch over the flat 48-step schedule. accS
// packed f16. Output rows stored exactly once (predicated f32x4). No atomics.
// ---------------------------------------------------------------------------
__global__ __launch_bounds__(256) void expert_kernel(
    const float* __restrict__ feat, const _Float16* __restrict__ wt,
    const float* __restrict__ eb1, const float* __restrict__ eb2,
    const float* __restrict__ eb3, const int* __restrict__ counts,
    const int* __restrict__ list, const float* __restrict__ wA,
    float* __restrict__ out) {
  __shared__ __align__(16) _Float16 A0[8192];   // [kt8][rt2][64][8], 16 KB
  __shared__ __align__(16) _Float16 Wk[8192];   // working image, 16 KB
  __shared__ int   toks[32];
  __shared__ float wgA[32];

  const int loT[15] = {0,0,1,0,1,2,0,1,2,3,0,1,2,3,4};
  const int hiT[15] = {1,2,2,3,3,3,4,4,4,4,5,5,5,5,5};

  int bid = blockIdx.x;
  int pid = 0, tile = 0, cnt = 0, cum = 0;
  #pragma unroll
  for (int i = 0; i < 15; ++i) {
    int ci = counts[i];
    int nt = (ci + 31) >> 5;
    bool hit = (bid >= cum) && (bid < cum + nt);
    if (hit) { pid = i; tile = bid - cum; cnt = ci; }
    cum += nt;
  }
  if (bid >= cum) return;
  int base = tile * 32;
  int eLo = loT[pid], eHi = hiT[pid];

  int tid = threadIdx.x;
  int wv = tid >> 6, L = tid & 63, m = L & 15, q = L >> 4;
  int wcol = wv * 64;

  // flat step s = pass*24 + l*8 + kt; B frag loader
  auto ldBs = [&](int s, int ct) -> f16x8 {
    int ee = (s >= 24) ? eHi : eLo;
    int ss = (s >= 24) ? s - 24 : s;
    return *(const f16x8*)(wt + ((size_t)ee * 24 + ss) * 8192 +
                           ((wv * 4 + ct) * 64 + L) * 8);
  };
  // depth-3 pipeline prologue
  f16x8 bq[3][4];
  #pragma unroll
  for (int ct = 0; ct < 4; ++ct) {
    bq[0][ct] = ldBs(0, ct);
    bq[1][ct] = ldBs(1, ct);
    bq[2][ct] = ldBs(2, ct);
  }

  if (tid < 32) {
    int idx = base + tid;
    int tk = 0; float a = 0.f;
    if (idx < cnt) { tk = list[pid * N_TOK + idx]; a = wA[pid * N_TOK + idx]; }
    toks[tid] = tk; wgA[tid] = a;
  }
  __syncthreads();                      // toks visible

  // stage A0: gather 32 token rows fp32 -> fp16 frag image (once)
  {
    int row = tid >> 3, seg = tid & 7;
    int rt = row >> 4, mm = row & 15;
    const float4* src = (const float4*)(feat + (size_t)toks[row] * 256 + seg * 32);
    #pragma unroll
    for (int i = 0; i < 4; ++i) {
      float4 a = src[2 * i], b = src[2 * i + 1];
      u32x4 pk;
      pk[0] = pack_f16x2(a.x, a.y);
      pk[1] = pack_f16x2(a.z, a.w);
      pk[2] = pack_f16x2(b.x, b.y);
      pk[3] = pack_f16x2(b.z, b.w);
      int k = seg * 32 + i * 8;
      int off = (((k >> 5) * 2 + rt) * 64 + ((k >> 3) & 3) * 16 + mm) * 8;
      *(u32x4*)(A0 + off) = pk;
    }
  }
  __syncthreads();                      // A0 ready

  f32x4 acc[2][4];
  f16x4 accS[2][4];                     // pass-0 weighted result, packed f16

  #pragma unroll
  for (int pass = 0; pass < 2; ++pass) {
    int e = pass ? eHi : eLo;
    const float* bias[3] = {eb1 + e * 256, eb2 + e * 256, eb3 + e * 256};

    #pragma unroll
    for (int l = 0; l < 3; ++l) {
      const _Float16* Asrc = (l == 0) ? A0 : Wk;
      #pragma unroll
      for (int ct = 0; ct < 4; ++ct) {
        float bv = bias[l][wcol + ct * 16 + m];
        #pragma unroll
        for (int rt = 0; rt < 2; ++rt) {
          acc[rt][ct][0] = bv; acc[rt][ct][1] = bv;
          acc[rt][ct][2] = bv; acc[rt][ct][3] = bv;
        }
      }
      #pragma unroll
      for (int kt = 0; kt < 8; ++kt) {
        int s = pass * 24 + l * 8 + kt;
        int slot = s % 3;
        f16x8 af[2];
        #pragma unroll
        for (int rt = 0; rt < 2; ++rt)
          af[rt] = *(const f16x8*)(Asrc + ((kt * 2 + rt) * 64 + L) * 8);
        #pragma unroll
        for (int rt = 0; rt < 2; ++rt)
          #pragma unroll
          for (int ct = 0; ct < 4; ++ct)
            acc[rt][ct] = __builtin_amdgcn_mfma_f32_16x16x32_f16(
                af[rt], bq[slot][ct], acc[rt][ct], 0, 0, 0);
        if (s + 3 < 48) {
          #pragma unroll
          for (int ct = 0; ct < 4; ++ct) bq[slot][ct] = ldBs(s + 3, ct);
        }
      }
      if (l < 2) {
        if (l == 1) __syncthreads();    // l1 reads Wk; drain before overwrite
        // 4x4 in-register transpose (shfl_xor) -> relu+pack -> b64 stores
        int i = m & 3;
        bool s1 = (i & 2) != 0, s2 = (i & 1) != 0;
        #pragma unroll
        for (int rt = 0; rt < 2; ++rt) {
          #pragma unroll
          for (int ct = 0; ct < 4; ++ct) {
            float x0 = acc[rt][ct][0], x1 = acc[rt][ct][1];
            float x2 = acc[rt][ct][2], x3 = acc[rt][ct][3];
            float t0 = __shfl_xor(x2, 2), t1 = __shfl_xor(x3, 2);
            float t2 = __shfl_xor(x0, 2), t3 = __shfl_xor(x1, 2);
            x0 = s1 ? t0 : x0;  x1 = s1 ? t1 : x1;
            x2 = s1 ? x2 : t2;  x3 = s1 ? x3 : t3;
            float u0 = __shfl_xor(x1, 1), u1 = __shfl_xor(x0, 1);
            float u2 = __shfl_xor(x3, 1), u3 = __shfl_xor(x2, 1);
            x0 = s2 ? u0 : x0;  x1 = s2 ? x1 : u1;
            x2 = s2 ? u2 : x2;  x3 = s2 ? x3 : u3;
            uint2 pk;
            pk.x = pack_f16x2(fmaxf(x0, 0.f), fmaxf(x1, 0.f));
            pk.y = pack_f16x2(fmaxf(x2, 0.f), fmaxf(x3, 0.f));
            int n0 = wcol + ct * 16 + (m & ~3);   // next-layer k base
            int m2 = q * 4 + i;                   // token row within tile rt
            int off = (((n0 >> 5) * 2 + rt) * 64 + ((n0 >> 3) & 3) * 16 + m2) * 8 +
                      (n0 & 7);
            *(uint2*)(Wk + off) = pk;
          }
        }
        __syncthreads();                // writeback visible
      }
    }

    if (pass == 0) {
      #pragma unroll
      for (int rt = 0; rt < 2; ++rt)
        #pragma unroll
        for (int r = 0; r < 4; ++r) {
          float wa = wgA[rt * 16 + q * 4 + r];
          #pragma unroll
          for (int ct = 0; ct < 4; ++ct)
            accS[rt][ct][r] = (_Float16)(acc[rt][ct][r] * wa);
        }
      __syncthreads();                  // pass-0 Wk reads done before pass-1 l0 writeback
    } else {
      #pragma unroll
      for (int rt = 0; rt < 2; ++rt)
        #pragma unroll
        for (int r = 0; r < 4; ++r) {
          float wb = 1.f - wgA[rt * 16 + q * 4 + r];
          #pragma unroll
          for (int ct = 0; ct < 4; ++ct)
            acc[rt][ct][r] = (float)accS[rt][ct][r] + acc[rt][ct][r] * wb;
        }
    }
  }

  // final DPP transpose + predicated f32x4 stores (each row exactly once)
  {
    int i = m & 3;
    bool s1 = (i & 2) != 0, s2 = (i & 1) != 0;
    #pragma unroll
    for (int rt = 0; rt < 2; ++rt) {
      int row = rt * 16 + q * 4 + i;
      bool valid = (base + row) < cnt;
      #pragma unroll
      for (int ct = 0; ct < 4; ++ct) {
        float x0 = acc[rt][ct][0], x1 = acc[rt][ct][1];
        float x2 = acc[rt][ct][2], x3 = acc[rt][ct][3];
        float t0 = __shfl_xor(x2, 2), t1 = __shfl_xor(x3, 2);
        float t2 = __shfl_xor(x0, 2), t3 = __shfl_xor(x1, 2);
        x0 = s1 ? t0 : x0;  x1 = s1 ? t1 : x1;
        x2 = s1 ? x2 : t2;  x3 = s1 ? x3 : t3;
        float u0 = __shfl_xor(x1, 1), u1 = __shfl_xor(x0, 1);
        float u2 = __shfl_xor(x3, 1), u3 = __shfl_xor(x2, 1);
        x0 = s2 ? u0 : x0;  x1 = s2 ? x1 : u1;
        x2 = s2 ? u2 : x2;  x3 = s2 ? x3 : u3;
        if (valid) {
          float4 v = make_float4(x0, x1, x2, x3);
          *(float4*)(out + (size_t)toks[row] * 256 + wcol + ct * 16 + (m & ~3)) = v;
        }
      }
    }
  }
}

extern "C" void kernel_launch(void* const* d_in, const int* in_sizes, int n_in,
                              void* d_out, int out_size, void* d_ws, size_t ws_size,
                              hipStream_t stream) {
  const float* feat = (const float*)d_in[0];
  const float* rw1  = (const float*)d_in[1];
  const float* rb1  = (const float*)d_in[2];
  const float* rw2  = (const float*)d_in[3];
  const float* rb2  = (const float*)d_in[4];
  const float* ew1  = (const float*)d_in[5];
  const float* eb1  = (const float*)d_in[6];
  const float* ew2  = (const float*)d_in[7];
  const float* eb2  = (const float*)d_in[8];
  const float* ew3  = (const float*)d_in[9];
  const float* eb3  = (const float*)d_in[10];
  float* out = (float*)d_out;

  char* ws = (char*)d_ws;
  int*      counts = (int*)(ws);
  int*      list   = (int*)(ws + WS_LIST);
  float*    wA     = (float*)(ws + WS_WA);
  _Float16* wt     = (_Float16*)(ws + WS_WT);
  _Float16* r1h    = (_Float16*)(ws + WS_R1H);
  _Float16* r1l    = (_Float16*)(ws + WS_R1L);

  convert_w_kernel<<<152, 256, 0, stream>>>(ew1, ew2, ew3, rw1, wt, r1h, r1l,
                                            counts);
  router_kernel<<<N_TOK / 32, 256, 0, stream>>>(feat, r1h, r1l, rb1, rw2, rb2,
                                                counts, list, wA);
  // 32768 tokens -> <=1024 full tiles + <=15 ragged: 1039 blocks covers all.
  expert_kernel<<<1039, 256, 0, stream>>>(
      feat, wt, eb1, eb2, eb3, counts, list, wA, out);
}